// Round 7
// baseline (240.634 us; speedup 1.0000x reference)
//
#include <hip/hip_runtime.h>
#include <math.h>

#define N1C 50176
#define N2C 12544
#define N3C 3136
#define NT_TILES (N2C * 8 / 64)   // 1568 col-tiles of 64

typedef __attribute__((ext_vector_type(8))) short bf16x8;
typedef __attribute__((ext_vector_type(4))) float f32x4;
typedef __attribute__((ext_vector_type(2))) unsigned uint2v;

__device__ __forceinline__ unsigned short f2bf(float f) {
    unsigned u = __builtin_bit_cast(unsigned, f);
    u += 0x7fffu + ((u >> 16) & 1u);
    return (unsigned short)(u >> 16);
}
__device__ __forceinline__ unsigned packbf(float a, float b) {
    return (unsigned)f2bf(a) | ((unsigned)f2bf(b) << 16);
}
__device__ __forceinline__ float bf2f(unsigned short u) {
    return __builtin_bit_cast(float, (unsigned)u << 16);
}
__device__ __forceinline__ float bflo(unsigned u) {
    return __builtin_bit_cast(float, u << 16);
}
__device__ __forceinline__ float bfhi(unsigned u) {
    return __builtin_bit_cast(float, u & 0xffff0000u);
}

// ---------------- fused prologue: transpose | mlp(off1+off2) | pad_w ----------------
#define TRB (N1C / 64)            // 784
#define MLB (2 * N2C * 9 / 256)   // 882
#define PWB 112

__device__ __forceinline__ void pad_one(int i, const float* __restrict__ W,
                                        unsigned short* __restrict__ Wp,
                                        int OC, int CIN, int KT) {
    int j = i & 7;
    int op = (i >> 3) & 31;
    int q = (i >> 8) & 3;
    int kt = (i >> 10) % KT;
    int g = i / (KT * 1024);
    int kp = kt * 32 + q * 8 + j;
    int t = kp / CIN, c = kp - t * CIN;
    int o = g * 32 + op;
    float v = (t < 9 && o < OC) ? W[(o * CIN + c) * 9 + t] : 0.f;
    Wp[i] = f2bf(v);
}

__global__ void prologue_kernel(const float* __restrict__ x, unsigned short* __restrict__ X0,
                                const float* __restrict__ off1, const float* __restrict__ off2,
                                const float* __restrict__ Wh, const float* __restrict__ bh,
                                const float* __restrict__ Wo, const float* __restrict__ bo,
                                float* __restrict__ A1, float* __restrict__ A2,
                                const float* __restrict__ W1, const float* __restrict__ W2,
                                const float* __restrict__ W3,
                                unsigned short* __restrict__ W1p, unsigned short* __restrict__ W2p,
                                unsigned short* __restrict__ W3p) {
    __shared__ float T[64][25];
    int blk = blockIdx.x;
    int tid = threadIdx.x;
    if (blk < TRB) {
        int n0 = blk * 64;
        for (int r = tid; r < 24 * 64; r += 256) {
            int cb = r >> 6;
            int nn = r & 63;
            T[nn][cb] = x[cb * N1C + n0 + nn];
        }
        __syncthreads();
        for (int w = tid; w < 64 * 24; w += 256) {
            int nn = w / 24;
            int u = w - nn * 24;
            X0[(n0 + nn) * 24 + u] = f2bf(T[nn][u]);
        }
    } else if (blk < TRB + MLB) {
        int idx = (blk - TRB) * 256 + tid;
        const float* offp;
        float* Ap;
        if (idx < N2C * 9) { offp = off1 + idx * 2; Ap = A1 + idx * 9; }
        else { int i2 = idx - N2C * 9; offp = off2 + i2 * 2; Ap = A2 + i2 * 9; }
        float o0 = offp[0], o1 = offp[1];
        float out[9];
#pragma unroll
        for (int t = 0; t < 9; t++) out[t] = bo[t];
#pragma unroll
        for (int h = 0; h < 32; h++) {
            float hv = fmaxf(o0 * Wh[h] + o1 * Wh[32 + h] + bh[h], 0.f);
#pragma unroll
            for (int t = 0; t < 9; t++) out[t] += hv * Wo[h * 9 + t];
        }
#pragma unroll
        for (int t = 0; t < 9; t++) Ap[t] = out[t];
    } else {
        int i = (blk - TRB - MLB) * 256 + tid;
        if (i < 1024) pad_one(i, W1, W1p, 32, 3, 1);
        else if (i < 10240) pad_one(i - 1024, W2, W2p, 32, 32, 9);
        else pad_one(i - 10240, W3, W3p, 64, 32, 9);
    }
}

// ---------------- MFMA + packed Y store (no BN epilogue) ----------------
template <int MW, int KT, int KSTR>
__device__ __forceinline__ void mfmaStore(const short* S, const unsigned short* Wp,
                                          const float* __restrict__ bias,
                                          unsigned short* __restrict__ Yb,
                                          int tile, int tid) {
    constexpr int OC = MW * 16;
    int lane = tid & 63, wv = tid >> 6, q = lane >> 4, cl = lane & 15;
    int colg = wv * 16 + cl;
    const bf16x8* wf = (const bf16x8*)Wp;
    f32x4 acc[MW];
#pragma unroll
    for (int m = 0; m < MW; m++) acc[m] = (f32x4){0.f, 0.f, 0.f, 0.f};
#pragma unroll
    for (int kt = 0; kt < KT; kt++) {
        bf16x8 bfr = *(const bf16x8*)&S[colg * KSTR + kt * 32 + q * 8];
#pragma unroll
        for (int m = 0; m < MW; m++) {
            const bf16x8* wg = wf + (m >> 1) * (KT * 128);
            bf16x8 am = wg[(kt * 4 + q) * 32 + cl + (m & 1) * 16];
            acc[m] = __builtin_amdgcn_mfma_f32_16x16x32_bf16(am, bfr, acc[m], 0, 0, 0);
        }
    }
    int C = tile * 64 + colg;
#pragma unroll
    for (int m = 0; m < MW; m++) {
        int ob = m * 16 + q * 4;
        float y0 = acc[m][0] + bias[ob + 0];
        float y1 = acc[m][1] + bias[ob + 1];
        float y2 = acc[m][2] + bias[ob + 2];
        float y3 = acc[m][3] + bias[ob + 3];
        uint2v uu;
        uu.x = packbf(y0, y1);
        uu.y = packbf(y2, y3);
        *(uint2v*)&Yb[(size_t)C * OC + ob] = uu;
    }
}

// ---------------- conv layer 1 (CIN=3, single tile) ----------------
__global__ __launch_bounds__(256, 4)
void conv1_kernel(const unsigned short* __restrict__ Xin,
                  const int* __restrict__ nbr,
                  const float* __restrict__ A,
                  const unsigned short* __restrict__ Wp,
                  const float* __restrict__ bias,
                  unsigned short* __restrict__ Yb) {
    constexpr int KSTR = 40;
    __shared__ alignas(16) short S[64 * KSTR];
    int tid = threadIdx.x;
    int n0 = blockIdx.x * 8;
    for (int i = tid; i < 64 * KSTR; i += 256) S[i] = 0;
    __syncthreads();
    if (tid < 192) {
        int nsub = tid / 24;
        int u = tid - nsub * 24;          // u = b*3+c
        int b = u / 3, c = u - b * 3;
        int n = n0 + nsub;
        const int* nb = nbr + n * 9;
        const float* Ar = A + n * 81;
        float f[9];
#pragma unroll
        for (int k = 0; k < 9; k++) f[k] = bf2f(Xin[nb[k] * 24 + u]);   // batch-issued
        float s[9];
#pragma unroll
        for (int t = 0; t < 9; t++) s[t] = 0.f;
#pragma unroll
        for (int k = 0; k < 9; k++)
#pragma unroll
            for (int t = 0; t < 9; t++) s[t] = fmaf(Ar[k * 9 + t], f[k], s[t]);
        int col = nsub * 8 + b;
#pragma unroll
        for (int t = 0; t < 9; t++) S[col * KSTR + t * 3 + c] = (short)f2bf(s[t]);
    }
    __syncthreads();
    mfmaStore<2, 1, KSTR>(S, Wp, bias, Yb, blockIdx.x, tid);
}

// ---------------- conv layers 2/3 (CIN=32): 2 tiles/block, cross-tile prefetch ----------------
#define KSTR32 296

__device__ __forceinline__ void gather36(unsigned* fu, const unsigned* __restrict__ Xu,
                                         const int* __restrict__ nbr, int nbase, int rem) {
#pragma unroll
    for (int g = 0; g < 4; g++)
#pragma unroll
        for (int k = 0; k < 9; k++) {
            int j = nbr[(nbase + g) * 9 + k];            // wave-uniform -> s_load
            fu[g * 9 + k] = Xu[(size_t)j * 128 + rem];   // coalesced uint
        }
}

template <bool HAS_BN>
__device__ __forceinline__ void phaseA32(const unsigned* fu, const float* __restrict__ A,
                                         int nbase, short* S, int nhalf, int b, int c2,
                                         float sc0, float sh0, float sc1, float sh1) {
#pragma unroll
    for (int g = 0; g < 4; g++) {
        const float* Ar = A + (nbase + g) * 81;
        float s0[9], s1[9];
#pragma unroll
        for (int t = 0; t < 9; t++) { s0[t] = 0.f; s1[t] = 0.f; }
#pragma unroll
        for (int k = 0; k < 9; k++) {
            unsigned u = fu[g * 9 + k];
            float lo = bflo(u), hi = bfhi(u);
            if (HAS_BN) {
                lo = fmaxf(fmaf(lo, sc0, sh0), 0.f);
                hi = fmaxf(fmaf(hi, sc1, sh1), 0.f);
            }
#pragma unroll
            for (int t = 0; t < 9; t++) {
                float a = Ar[k * 9 + t];
                s0[t] = fmaf(a, lo, s0[t]);
                s1[t] = fmaf(a, hi, s1[t]);
            }
        }
        int col = (nhalf * 4 + g) * 8 + b;
        unsigned* Srow = (unsigned*)&S[col * KSTR32];
#pragma unroll
        for (int t = 0; t < 9; t++) Srow[t * 16 + c2] = packbf(s0[t], s1[t]);
    }
}

template <int MW, bool HAS_BN>
__global__ __launch_bounds__(256, 4)
void conv32_kernel(const unsigned short* __restrict__ Xin,
                   const int* __restrict__ nbr,
                   const float* __restrict__ A,
                   const unsigned short* __restrict__ Wp,
                   const float* __restrict__ bias,
                   const float* __restrict__ bnsc,
                   const float* __restrict__ bnsh,
                   unsigned short* __restrict__ Yb) {
    __shared__ alignas(16) short S[64 * KSTR32];
    int tid = threadIdx.x;
    int nhalf = __builtin_amdgcn_readfirstlane(tid >> 7);   // wave-uniform
    int rem = tid & 127;
    int b = rem >> 4, c2 = rem & 15;
    float sc0 = 1.f, sh0 = 0.f, sc1 = 1.f, sh1 = 0.f;
    if (HAS_BN) {
        sc0 = bnsc[2 * c2]; sc1 = bnsc[2 * c2 + 1];
        sh0 = bnsh[2 * c2]; sh1 = bnsh[2 * c2 + 1];
    }
    const unsigned* Xu = (const unsigned*)Xin;
    int tile0 = blockIdx.x * 2;
    int tile1 = tile0 + 1;
    int nb0 = tile0 * 8 + nhalf * 4;
    int nb1 = tile1 * 8 + nhalf * 4;

    unsigned fu[36];
    gather36(fu, Xu, nbr, nb0, rem);
    phaseA32<HAS_BN>(fu, A, nb0, S, nhalf, b, c2, sc0, sh0, sc1, sh1);
    __syncthreads();

    unsigned fu2[36];
    gather36(fu2, Xu, nbr, nb1, rem);          // in flight during tile0 MFMA
    mfmaStore<MW, 9, KSTR32>(S, Wp, bias, Yb, tile0, tid);
    __syncthreads();                            // S reads done

    phaseA32<HAS_BN>(fu2, A, nb1, S, nhalf, b, c2, sc0, sh0, sc1, sh1);
    __syncthreads();
    mfmaStore<MW, 9, KSTR32>(S, Wp, bias, Yb, tile1, tid);
}

// ---------------- BN sum over Yb: 128 blocks -> Part[2*OC][128] ----------------
template <int OC>
__global__ __launch_bounds__(256, 8)
void bn_sum(const unsigned short* __restrict__ Yb, double* __restrict__ Part) {
    constexpr int CLS = OC / 2;
    constexpr int TOTU = N2C * 8 * OC / 2;   // uint count (exactly divisible by 32768)
    const unsigned* Yu = (const unsigned*)Yb;
    int tid = threadIdx.x;
    double s0 = 0, q0 = 0, s1 = 0, q1 = 0;
    for (int p = blockIdx.x * 256 + tid; p < TOTU; p += 128 * 256) {
        unsigned u = Yu[p];
        double lo = (double)bflo(u), hi = (double)bfhi(u);
        s0 += lo; q0 += lo * lo;
        s1 += hi; q1 += hi * hi;
    }
#pragma unroll
    for (int d = CLS; d < 64; d <<= 1) {
        s0 += __shfl_xor(s0, d); q0 += __shfl_xor(q0, d);
        s1 += __shfl_xor(s1, d); q1 += __shfl_xor(q1, d);
    }
    __shared__ double red[4][CLS][4];
    int wv = tid >> 6, lane = tid & 63;
    if (lane < CLS) {
        red[wv][lane][0] = s0; red[wv][lane][1] = q0;
        red[wv][lane][2] = s1; red[wv][lane][3] = q1;
    }
    __syncthreads();
    if (tid < 2 * OC) {
        int o = (tid < OC) ? tid : tid - OC;
        int isq = (tid >= OC) ? 1 : 0;
        int cls = o >> 1, slot = (o & 1) * 2 + isq;
        double v = red[0][cls][slot] + red[1][cls][slot] + red[2][cls][slot] + red[3][cls][slot];
        Part[(size_t)tid * 128 + blockIdx.x] = v;
    }
}

// ---------------- BN finalize: one block (64 thr) per channel ----------------
__global__ void bn_fin(const double* __restrict__ Part,
                       const float* __restrict__ g, const float* __restrict__ be,
                       float* __restrict__ sc, float* __restrict__ sh, int OC) {
    int o = blockIdx.x;
    int t = threadIdx.x;   // 64
    double s = Part[(size_t)o * 128 + t] + Part[(size_t)o * 128 + t + 64];
    double q = Part[(size_t)(OC + o) * 128 + t] + Part[(size_t)(OC + o) * 128 + t + 64];
#pragma unroll
    for (int d = 1; d < 64; d <<= 1) {
        s += __shfl_xor(s, d);
        q += __shfl_xor(q, d);
    }
    if (t == 0) {
        double cnt = (double)N2C * 8.0;
        double mean = s / cnt;
        double var = q / cnt - mean * mean;
        double rs = 1.0 / sqrt(var + 1e-5);
        double scale = (double)g[o] * rs;
        sc[o] = (float)scale;
        sh[o] = (float)((double)be[o] - mean * scale);
    }
}

// ---------------- pool: 8 m per block ----------------
__global__ __launch_bounds__(512, 4)
void pool_kernel(const unsigned short* __restrict__ Y3, const int* __restrict__ pidx,
                 const float* __restrict__ sc, const float* __restrict__ sh,
                 float* __restrict__ out) {
    int m0 = blockIdx.x * 8;
    int tid = threadIdx.x;      // b*64 + o
    int o = tid & 63;
    float s = sc[o], h = sh[o];
    float mx[8];
    int jn[9];
#pragma unroll
    for (int k = 0; k < 9; k++) jn[k] = pidx[m0 * 9 + k];
#pragma unroll 1
    for (int mi = 0; mi < 8; mi++) {
        int jc[9];
#pragma unroll
        for (int k = 0; k < 9; k++) jc[k] = jn[k];
        if (mi < 7) {
#pragma unroll
            for (int k = 0; k < 9; k++) jn[k] = pidx[(m0 + mi + 1) * 9 + k];
        }
        float v0 = 0.f;
#pragma unroll
        for (int k = 0; k < 9; k++) {
            float v = bf2f(Y3[(size_t)jc[k] * 512 + tid]);
            v0 = fmaxf(v0, fmaf(v, s, h));
        }
        mx[mi] = fmaxf(v0, 0.f);
    }
    float* op = out + (size_t)tid * 3136 + m0;
#pragma unroll
    for (int mi = 0; mi < 8; mi++) op[mi] = mx[mi];
}

extern "C" void kernel_launch(void* const* d_in, const int* in_sizes, int n_in,
                              void* d_out, int out_size, void* d_ws, size_t ws_size,
                              hipStream_t stream) {
    const float* x    = (const float*)d_in[0];
    const int*   nbr1 = (const int*)d_in[1];
    const float* off1 = (const float*)d_in[2];
    const int*   nbr2 = (const int*)d_in[3];
    const float* off2 = (const float*)d_in[4];
    const int*   pidx = (const int*)d_in[5];
    const float* Wh   = (const float*)d_in[6];
    const float* bh   = (const float*)d_in[7];
    const float* Wo   = (const float*)d_in[8];
    const float* bo   = (const float*)d_in[9];
    const float* W1   = (const float*)d_in[10];
    const float* b1   = (const float*)d_in[11];
    const float* W2   = (const float*)d_in[12];
    const float* b2   = (const float*)d_in[13];
    const float* W3   = (const float*)d_in[14];
    const float* b3   = (const float*)d_in[15];
    const float* g1   = (const float*)d_in[16];
    const float* be1  = (const float*)d_in[17];
    const float* g2   = (const float*)d_in[18];
    const float* be2  = (const float*)d_in[19];
    const float* g3   = (const float*)d_in[20];
    const float* be3  = (const float*)d_in[21];

    char* ws = (char*)d_ws;
    size_t off = 0;
    auto alloc = [&](size_t bytes) -> void* {
        void* p = ws + off;
        off += (bytes + 255) & ~(size_t)255;
        return p;
    };
    unsigned short* X0b = (unsigned short*)alloc((size_t)N1C * 24 * 2);
    float* A1 = (float*)alloc((size_t)N2C * 81 * 4);
    float* A2 = (float*)alloc((size_t)N2C * 81 * 4);
    unsigned short* Y1b = (unsigned short*)alloc((size_t)N2C * 8 * 32 * 2);
    unsigned short* Y2b = (unsigned short*)alloc((size_t)N2C * 8 * 32 * 2);
    unsigned short* Y3b = (unsigned short*)alloc((size_t)N2C * 8 * 64 * 2);
    unsigned short* W1p = (unsigned short*)alloc(32 * 32 * 2);
    unsigned short* W2p = (unsigned short*)alloc(32 * 288 * 2);
    unsigned short* W3p = (unsigned short*)alloc(64 * 288 * 2);
    double* Part  = (double*)alloc(128 * 128 * 8);
    float*  scbuf = (float*)alloc(256 * 4);

    float* sc1 = scbuf;       float* sh1 = scbuf + 32;
    float* sc2 = scbuf + 64;  float* sh2 = scbuf + 96;
    float* sc3 = scbuf + 128; float* sh3 = scbuf + 192;

    prologue_kernel<<<TRB + MLB + PWB, 256, 0, stream>>>(
        x, X0b, off1, off2, Wh, bh, Wo, bo, A1, A2, W1, W2, W3, W1p, W2p, W3p);

    conv1_kernel<<<NT_TILES, 256, 0, stream>>>(X0b, nbr1, A1, W1p, b1, Y1b);
    bn_sum<32><<<128, 256, 0, stream>>>(Y1b, Part);
    bn_fin<<<32, 64, 0, stream>>>(Part, g1, be1, sc1, sh1, 32);

    conv32_kernel<2, true><<<NT_TILES / 2, 256, 0, stream>>>(
        Y1b, nbr2, A2, W2p, b2, sc1, sh1, Y2b);
    bn_sum<32><<<128, 256, 0, stream>>>(Y2b, Part);
    bn_fin<<<32, 64, 0, stream>>>(Part, g2, be2, sc2, sh2, 32);

    conv32_kernel<4, true><<<NT_TILES / 2, 256, 0, stream>>>(
        Y2b, nbr2, A2, W3p, b3, sc2, sh2, Y3b);
    bn_sum<64><<<128, 256, 0, stream>>>(Y3b, Part);
    bn_fin<<<64, 64, 0, stream>>>(Part, g3, be3, sc3, sh3, 64);

    pool_kernel<<<N3C / 8, 512, 0, stream>>>(Y3b, pidx, sc3, sh3, (float*)d_out);
}

// Round 8
// 227.853 us; speedup vs baseline: 1.0561x; 1.0561x over previous
//
#include <hip/hip_runtime.h>
#include <math.h>

#define N1C 50176
#define N2C 12544
#define N3C 3136
#define NT_TILES (N2C * 8 / 64)   // 1568 col-tiles of 64 (conv1)

typedef __attribute__((ext_vector_type(8))) short bf16x8;
typedef __attribute__((ext_vector_type(4))) float f32x4;
typedef __attribute__((ext_vector_type(2))) unsigned uint2v;

__device__ __forceinline__ unsigned short f2bf(float f) {
    unsigned u = __builtin_bit_cast(unsigned, f);
    u += 0x7fffu + ((u >> 16) & 1u);
    return (unsigned short)(u >> 16);
}
__device__ __forceinline__ unsigned packbf(float a, float b) {
    return (unsigned)f2bf(a) | ((unsigned)f2bf(b) << 16);
}
__device__ __forceinline__ float bf2f(unsigned short u) {
    return __builtin_bit_cast(float, (unsigned)u << 16);
}
__device__ __forceinline__ float bflo(unsigned u) {
    return __builtin_bit_cast(float, u << 16);
}
__device__ __forceinline__ float bfhi(unsigned u) {
    return __builtin_bit_cast(float, u & 0xffff0000u);
}

// ---------------- fused prologue: transpose | mlp(off1+off2) | pad_w ----------------
#define TRB (N1C / 64)            // 784
#define MLB (2 * N2C * 9 / 256)   // 882
#define PWB 112

__device__ __forceinline__ void pad_one(int i, const float* __restrict__ W,
                                        unsigned short* __restrict__ Wp,
                                        int OC, int CIN, int KT) {
    int j = i & 7;
    int op = (i >> 3) & 31;
    int q = (i >> 8) & 3;
    int kt = (i >> 10) % KT;
    int g = i / (KT * 1024);
    int kp = kt * 32 + q * 8 + j;
    int t = kp / CIN, c = kp - t * CIN;
    int o = g * 32 + op;
    float v = (t < 9 && o < OC) ? W[(o * CIN + c) * 9 + t] : 0.f;
    Wp[i] = f2bf(v);
}

__global__ void prologue_kernel(const float* __restrict__ x, unsigned short* __restrict__ X0,
                                const float* __restrict__ off1, const float* __restrict__ off2,
                                const float* __restrict__ Wh, const float* __restrict__ bh,
                                const float* __restrict__ Wo, const float* __restrict__ bo,
                                float* __restrict__ A1, float* __restrict__ A2,
                                const float* __restrict__ W1, const float* __restrict__ W2,
                                const float* __restrict__ W3,
                                unsigned short* __restrict__ W1p, unsigned short* __restrict__ W2p,
                                unsigned short* __restrict__ W3p) {
    __shared__ float T[64][25];
    int blk = blockIdx.x;
    int tid = threadIdx.x;
    if (blk < TRB) {
        int n0 = blk * 64;
        for (int r = tid; r < 24 * 64; r += 256) {
            int cb = r >> 6;
            int nn = r & 63;
            T[nn][cb] = x[cb * N1C + n0 + nn];
        }
        __syncthreads();
        for (int w = tid; w < 64 * 24; w += 256) {
            int nn = w / 24;
            int u = w - nn * 24;
            X0[(n0 + nn) * 24 + u] = f2bf(T[nn][u]);
        }
    } else if (blk < TRB + MLB) {
        int idx = (blk - TRB) * 256 + tid;
        const float* offp;
        float* Ap;
        if (idx < N2C * 9) { offp = off1 + idx * 2; Ap = A1 + idx * 9; }
        else { int i2 = idx - N2C * 9; offp = off2 + i2 * 2; Ap = A2 + i2 * 9; }
        float o0 = offp[0], o1 = offp[1];
        float out[9];
#pragma unroll
        for (int t = 0; t < 9; t++) out[t] = bo[t];
#pragma unroll
        for (int h = 0; h < 32; h++) {
            float hv = fmaxf(o0 * Wh[h] + o1 * Wh[32 + h] + bh[h], 0.f);
#pragma unroll
            for (int t = 0; t < 9; t++) out[t] += hv * Wo[h * 9 + t];
        }
#pragma unroll
        for (int t = 0; t < 9; t++) Ap[t] = out[t];
    } else {
        int i = (blk - TRB - MLB) * 256 + tid;
        if (i < 1024) pad_one(i, W1, W1p, 32, 3, 1);
        else if (i < 10240) pad_one(i - 1024, W2, W2p, 32, 32, 9);
        else pad_one(i - 10240, W3, W3p, 64, 32, 9);
    }
}

// ---------------- conv layer 1 (CIN=3, 64 cols, plain Y store) ----------------
__global__ __launch_bounds__(256, 8)
void conv1_kernel(const unsigned short* __restrict__ Xin,
                  const int* __restrict__ nbr,
                  const float* __restrict__ A,
                  const unsigned short* __restrict__ Wp,
                  const float* __restrict__ bias,
                  unsigned short* __restrict__ Yb) {
    constexpr int KSTR = 40;
    __shared__ alignas(16) short S[64 * KSTR];
    int tid = threadIdx.x;
    int n0 = blockIdx.x * 8;
    for (int i = tid; i < 64 * KSTR; i += 256) S[i] = 0;
    __syncthreads();
    if (tid < 192) {
        int nsub = tid / 24;
        int u = tid - nsub * 24;          // u = b*3+c
        int b = u / 3, c = u - b * 3;
        int n = n0 + nsub;
        const int* nb = nbr + n * 9;
        const float* Ar = A + n * 81;
        float f[9];
#pragma unroll
        for (int k = 0; k < 9; k++) f[k] = bf2f(Xin[nb[k] * 24 + u]);
        float s[9];
#pragma unroll
        for (int t = 0; t < 9; t++) s[t] = 0.f;
#pragma unroll
        for (int k = 0; k < 9; k++)
#pragma unroll
            for (int t = 0; t < 9; t++) s[t] = fmaf(Ar[k * 9 + t], f[k], s[t]);
        int col = nsub * 8 + b;
#pragma unroll
        for (int t = 0; t < 9; t++) S[col * KSTR + t * 3 + c] = (short)f2bf(s[t]);
    }
    __syncthreads();
    // MFMA: wave wv covers cols wv*16..+15, both M-tiles (OC=32)
    int lane = tid & 63, wv = tid >> 6, q = lane >> 4, cl = lane & 15;
    int colg = wv * 16 + cl;
    const bf16x8* wf = (const bf16x8*)Wp;
    f32x4 acc0 = {0.f, 0.f, 0.f, 0.f};
    f32x4 acc1 = {0.f, 0.f, 0.f, 0.f};
    bf16x8 bfr = *(const bf16x8*)&S[colg * KSTR + q * 8];
    bf16x8 a0 = wf[q * 32 + cl];
    bf16x8 a1 = wf[q * 32 + cl + 16];
    acc0 = __builtin_amdgcn_mfma_f32_16x16x32_bf16(a0, bfr, acc0, 0, 0, 0);
    acc1 = __builtin_amdgcn_mfma_f32_16x16x32_bf16(a1, bfr, acc1, 0, 0, 0);
    int C = blockIdx.x * 64 + colg;
#pragma unroll
    for (int m = 0; m < 2; m++) {
        f32x4 ac = m ? acc1 : acc0;
        int ob = m * 16 + q * 4;
        uint2v uu;
        uu.x = packbf(ac[0] + bias[ob + 0], ac[1] + bias[ob + 1]);
        uu.y = packbf(ac[2] + bias[ob + 2], ac[3] + bias[ob + 3]);
        *(uint2v*)&Yb[(size_t)C * 32 + ob] = uu;
    }
}

// ---------------- conv layers 2/3 (CIN=32): 32-col tile, 8 blocks/CU ----------------
#define KSTR32 296

template <int MW, bool HAS_BN>   // MW = OC/16
__global__ __launch_bounds__(256, 8)
void conv32_kernel(const unsigned short* __restrict__ Xin,
                   const int* __restrict__ nbr,
                   const float* __restrict__ A,
                   const unsigned short* __restrict__ Wp,
                   const float* __restrict__ bias,
                   const float* __restrict__ bnsc,
                   const float* __restrict__ bnsh,
                   unsigned short* __restrict__ Yb) {
    constexpr int OC = MW * 16;
    constexpr int MPW = MW / 2;          // M-tiles per wave
    __shared__ alignas(16) short S[32 * KSTR32];   // 18,944 B -> 8 blocks/CU

    int tid = threadIdx.x;
    int n0 = blockIdx.x * 4;
    int nsel = __builtin_amdgcn_readfirstlane(tid >> 7);   // wave-uniform: node pair
    int rem = tid & 127;
    int b = rem >> 4, c2 = rem & 15;
    float sc0 = 1.f, sh0 = 0.f, sc1 = 1.f, sh1 = 0.f;
    if (HAS_BN) {
        sc0 = bnsc[2 * c2]; sc1 = bnsc[2 * c2 + 1];
        sh0 = bnsh[2 * c2]; sh1 = bnsh[2 * c2 + 1];
    }
    const unsigned* Xu = (const unsigned*)Xin;

    // ---- phase A: 2 nodes/thread, all 18 gathers issued upfront ----
    unsigned fu[18];
#pragma unroll
    for (int g = 0; g < 2; g++)
#pragma unroll
        for (int k = 0; k < 9; k++) {
            int j = nbr[(n0 + nsel * 2 + g) * 9 + k];     // wave-uniform -> s_load
            fu[g * 9 + k] = Xu[(size_t)j * 128 + rem];    // coalesced uint
        }
#pragma unroll
    for (int g = 0; g < 2; g++) {
        const float* Ar = A + (n0 + nsel * 2 + g) * 81;
        float s0[9], s1[9];
#pragma unroll
        for (int t = 0; t < 9; t++) { s0[t] = 0.f; s1[t] = 0.f; }
#pragma unroll
        for (int k = 0; k < 9; k++) {
            unsigned u = fu[g * 9 + k];
            float lo = bflo(u), hi = bfhi(u);
            if (HAS_BN) {
                lo = fmaxf(fmaf(lo, sc0, sh0), 0.f);
                hi = fmaxf(fmaf(hi, sc1, sh1), 0.f);
            }
#pragma unroll
            for (int t = 0; t < 9; t++) {
                float a = Ar[k * 9 + t];
                s0[t] = fmaf(a, lo, s0[t]);
                s1[t] = fmaf(a, hi, s1[t]);
            }
        }
        int col = (nsel * 2 + g) * 8 + b;
        unsigned* Srow = (unsigned*)&S[col * KSTR32];
#pragma unroll
        for (int t = 0; t < 9; t++) Srow[t * 16 + c2] = packbf(s0[t], s1[t]);
    }
    __syncthreads();

    // ---- phase B: wave = (col-half, M-pair) ----
    int lane = tid & 63, wv = tid >> 6, q = lane >> 4, cl = lane & 15;
    int colg = (wv & 1) * 16 + cl;
    int mbase = (wv >> 1) * MPW;
    const bf16x8* wf = (const bf16x8*)Wp;
    f32x4 acc[MPW];
#pragma unroll
    for (int mi = 0; mi < MPW; mi++) acc[mi] = (f32x4){0.f, 0.f, 0.f, 0.f};
#pragma unroll
    for (int kt = 0; kt < 9; kt++) {
        bf16x8 bfr = *(const bf16x8*)&S[colg * KSTR32 + kt * 32 + q * 8];
#pragma unroll
        for (int mi = 0; mi < MPW; mi++) {
            int m = mbase + mi;
            const bf16x8* wg = wf + (m >> 1) * (9 * 128);
            bf16x8 am = wg[(kt * 4 + q) * 32 + cl + (m & 1) * 16];
            acc[mi] = __builtin_amdgcn_mfma_f32_16x16x32_bf16(am, bfr, acc[mi], 0, 0, 0);
        }
    }
    int C = blockIdx.x * 32 + colg;
#pragma unroll
    for (int mi = 0; mi < MPW; mi++) {
        int ob = (mbase + mi) * 16 + q * 4;
        uint2v uu;
        uu.x = packbf(acc[mi][0] + bias[ob + 0], acc[mi][1] + bias[ob + 1]);
        uu.y = packbf(acc[mi][2] + bias[ob + 2], acc[mi][3] + bias[ob + 3]);
        *(uint2v*)&Yb[(size_t)C * OC + ob] = uu;
    }
}

// ---------------- BN sum over Yb: 128 blocks -> Part[2*OC][128] ----------------
template <int OC>
__global__ __launch_bounds__(256, 8)
void bn_sum(const unsigned short* __restrict__ Yb, double* __restrict__ Part) {
    constexpr int CLS = OC / 2;
    constexpr int TOTU = N2C * 8 * OC / 2;
    const unsigned* Yu = (const unsigned*)Yb;
    int tid = threadIdx.x;
    double s0 = 0, q0 = 0, s1 = 0, q1 = 0;
    for (int p = blockIdx.x * 256 + tid; p < TOTU; p += 128 * 256) {
        unsigned u = Yu[p];
        double lo = (double)bflo(u), hi = (double)bfhi(u);
        s0 += lo; q0 += lo * lo;
        s1 += hi; q1 += hi * hi;
    }
#pragma unroll
    for (int d = CLS; d < 64; d <<= 1) {
        s0 += __shfl_xor(s0, d); q0 += __shfl_xor(q0, d);
        s1 += __shfl_xor(s1, d); q1 += __shfl_xor(q1, d);
    }
    __shared__ double red[4][CLS][4];
    int wv = tid >> 6, lane = tid & 63;
    if (lane < CLS) {
        red[wv][lane][0] = s0; red[wv][lane][1] = q0;
        red[wv][lane][2] = s1; red[wv][lane][3] = q1;
    }
    __syncthreads();
    if (tid < 2 * OC) {
        int o = (tid < OC) ? tid : tid - OC;
        int isq = (tid >= OC) ? 1 : 0;
        int cls = o >> 1, slot = (o & 1) * 2 + isq;
        double v = red[0][cls][slot] + red[1][cls][slot] + red[2][cls][slot] + red[3][cls][slot];
        Part[(size_t)tid * 128 + blockIdx.x] = v;
    }
}

// ---------------- BN finalize: one block (64 thr) per channel ----------------
__global__ void bn_fin(const double* __restrict__ Part,
                       const float* __restrict__ g, const float* __restrict__ be,
                       float* __restrict__ sc, float* __restrict__ sh, int OC) {
    int o = blockIdx.x;
    int t = threadIdx.x;   // 64
    double s = Part[(size_t)o * 128 + t] + Part[(size_t)o * 128 + t + 64];
    double q = Part[(size_t)(OC + o) * 128 + t] + Part[(size_t)(OC + o) * 128 + t + 64];
#pragma unroll
    for (int d = 1; d < 64; d <<= 1) {
        s += __shfl_xor(s, d);
        q += __shfl_xor(q, d);
    }
    if (t == 0) {
        double cnt = (double)N2C * 8.0;
        double mean = s / cnt;
        double var = q / cnt - mean * mean;
        double rs = 1.0 / sqrt(var + 1e-5);
        double scale = (double)g[o] * rs;
        sc[o] = (float)scale;
        sh[o] = (float)((double)be[o] - mean * scale);
    }
}

// ---------------- pool: 8 m per block ----------------
__global__ __launch_bounds__(512, 4)
void pool_kernel(const unsigned short* __restrict__ Y3, const int* __restrict__ pidx,
                 const float* __restrict__ sc, const float* __restrict__ sh,
                 float* __restrict__ out) {
    int m0 = blockIdx.x * 8;
    int tid = threadIdx.x;      // b*64 + o
    int o = tid & 63;
    float s = sc[o], h = sh[o];
    float mx[8];
    int jn[9];
#pragma unroll
    for (int k = 0; k < 9; k++) jn[k] = pidx[m0 * 9 + k];
#pragma unroll 1
    for (int mi = 0; mi < 8; mi++) {
        int jc[9];
#pragma unroll
        for (int k = 0; k < 9; k++) jc[k] = jn[k];
        if (mi < 7) {
#pragma unroll
            for (int k = 0; k < 9; k++) jn[k] = pidx[(m0 + mi + 1) * 9 + k];
        }
        float v0 = 0.f;
#pragma unroll
        for (int k = 0; k < 9; k++) {
            float v = bf2f(Y3[(size_t)jc[k] * 512 + tid]);
            v0 = fmaxf(v0, fmaf(v, s, h));
        }
        mx[mi] = fmaxf(v0, 0.f);
    }
    float* op = out + (size_t)tid * 3136 + m0;
#pragma unroll
    for (int mi = 0; mi < 8; mi++) op[mi] = mx[mi];
}

extern "C" void kernel_launch(void* const* d_in, const int* in_sizes, int n_in,
                              void* d_out, int out_size, void* d_ws, size_t ws_size,
                              hipStream_t stream) {
    const float* x    = (const float*)d_in[0];
    const int*   nbr1 = (const int*)d_in[1];
    const float* off1 = (const float*)d_in[2];
    const int*   nbr2 = (const int*)d_in[3];
    const float* off2 = (const float*)d_in[4];
    const int*   pidx = (const int*)d_in[5];
    const float* Wh   = (const float*)d_in[6];
    const float* bh   = (const float*)d_in[7];
    const float* Wo   = (const float*)d_in[8];
    const float* bo   = (const float*)d_in[9];
    const float* W1   = (const float*)d_in[10];
    const float* b1   = (const float*)d_in[11];
    const float* W2   = (const float*)d_in[12];
    const float* b2   = (const float*)d_in[13];
    const float* W3   = (const float*)d_in[14];
    const float* b3   = (const float*)d_in[15];
    const float* g1   = (const float*)d_in[16];
    const float* be1  = (const float*)d_in[17];
    const float* g2   = (const float*)d_in[18];
    const float* be2  = (const float*)d_in[19];
    const float* g3   = (const float*)d_in[20];
    const float* be3  = (const float*)d_in[21];

    char* ws = (char*)d_ws;
    size_t off = 0;
    auto alloc = [&](size_t bytes) -> void* {
        void* p = ws + off;
        off += (bytes + 255) & ~(size_t)255;
        return p;
    };
    unsigned short* X0b = (unsigned short*)alloc((size_t)N1C * 24 * 2);
    float* A1 = (float*)alloc((size_t)N2C * 81 * 4);
    float* A2 = (float*)alloc((size_t)N2C * 81 * 4);
    unsigned short* Y1b = (unsigned short*)alloc((size_t)N2C * 8 * 32 * 2);
    unsigned short* Y2b = (unsigned short*)alloc((size_t)N2C * 8 * 32 * 2);
    unsigned short* Y3b = (unsigned short*)alloc((size_t)N2C * 8 * 64 * 2);
    unsigned short* W1p = (unsigned short*)alloc(32 * 32 * 2);
    unsigned short* W2p = (unsigned short*)alloc(32 * 288 * 2);
    unsigned short* W3p = (unsigned short*)alloc(64 * 288 * 2);
    double* Part  = (double*)alloc(128 * 128 * 8);
    float*  scbuf = (float*)alloc(256 * 4);

    float* sc1 = scbuf;       float* sh1 = scbuf + 32;
    float* sc2 = scbuf + 64;  float* sh2 = scbuf + 96;
    float* sc3 = scbuf + 128; float* sh3 = scbuf + 192;

    prologue_kernel<<<TRB + MLB + PWB, 256, 0, stream>>>(
        x, X0b, off1, off2, Wh, bh, Wo, bo, A1, A2, W1, W2, W3, W1p, W2p, W3p);

    conv1_kernel<<<NT_TILES, 256, 0, stream>>>(X0b, nbr1, A1, W1p, b1, Y1b);
    bn_sum<32><<<128, 256, 0, stream>>>(Y1b, Part);
    bn_fin<<<32, 64, 0, stream>>>(Part, g1, be1, sc1, sh1, 32);

    conv32_kernel<2, true><<<N2C / 4, 256, 0, stream>>>(
        Y1b, nbr2, A2, W2p, b2, sc1, sh1, Y2b);
    bn_sum<32><<<128, 256, 0, stream>>>(Y2b, Part);
    bn_fin<<<32, 64, 0, stream>>>(Part, g2, be2, sc2, sh2, 32);

    conv32_kernel<4, true><<<N2C / 4, 256, 0, stream>>>(
        Y2b, nbr2, A2, W3p, b3, sc2, sh2, Y3b);
    bn_sum<64><<<128, 256, 0, stream>>>(Y3b, Part);
    bn_fin<<<64, 64, 0, stream>>>(Part, g3, be3, sc3, sh3, 64);

    pool_kernel<<<N3C / 8, 512, 0, stream>>>(Y3b, pidx, sc3, sh3, (float*)d_out);
}